// Round 4
// baseline (4994.827 us; speedup 1.0000x reference)
//
#include <hip/hip_runtime.h>
#include <stdint.h>

typedef unsigned long long u64;
typedef unsigned int u32;
using i32x4  = __attribute__((ext_vector_type(4))) int;
using i32x16 = __attribute__((ext_vector_type(16))) int;
using f32x4  = __attribute__((ext_vector_type(4))) float;

#define HW 16384   // 128*128

// workspace byte offsets (total ~75.1 MB)
#define OFF_R      0ull           // f32 [16][64][16384] r written by k_head
#define OFF_SG0    67108864ull    // u64 [16][16384] sign ping (also fallback sgR)
#define OFF_SG1    69206016ull    // u64 [16][16384] sign pong (also fallback sgT)
#define OFF_NZT    71303168ull    // u64 [16][16384] fallback nz; first 64 B = barrier (persistent path)
#define OFF_WBSG   73400320ull    // i8  [33][9 tap][64 oc][64 ci] sign weights
#define OFF_ALPHA  74616832ull    // f32 [33][64]
#define OFF_WEFF   74625280ull    // f32 110592 composed tail weights

// ---------------- prep: i8 sign-weight tensor [conv][tap][oc][ci] + alpha ----------------
__global__ __launch_bounds__(256) void k_prep_wbsg(const float* __restrict__ wbody, const float* __restrict__ wlast,
                                                   signed char* __restrict__ wB, float* __restrict__ alpha){
  int t = blockIdx.x*256 + threadIdx.x;          // 33*9*64 = 19008
  if (t >= 33*9*64) return;
  int o = t & 63, tap = (t>>6)%9, cid = t/(64*9);
  const float* src = (cid < 32) ? (wbody + (size_t)cid*36864) : wlast;   // [o][ci][9]
  u32 d[16];
  #pragma unroll
  for (int c4=0;c4<16;c4++){
    u32 v=0;
    #pragma unroll
    for (int j=0;j<4;j++){
      float w = src[(o*64 + c4*4+j)*9 + tap];
      v |= ((w < 0.f) ? 0xFFu : 0x01u) << (8*j);
    }
    d[c4]=v;
  }
  i32x4* dst = (i32x4*)(wB + ((size_t)(cid*9+tap)*64 + o)*64);
  #pragma unroll
  for (int k=0;k<4;k++){ i32x4 v; v[0]=(int)d[4*k]; v[1]=(int)d[4*k+1]; v[2]=(int)d[4*k+2]; v[3]=(int)d[4*k+3]; dst[k]=v; }
  if (tap==0){
    float s=0.f;
    for (int ci=0;ci<64;ci++)
      #pragma unroll
      for (int tp=0;tp<9;tp++) s += fabsf(src[(o*64+ci)*9+tp]);
    alpha[cid*64+o] = s * (1.0f/576.0f);
  }
}

// ------- prep: composed up->shuffle->tail weights (9 edge variants) -------
__global__ __launch_bounds__(256) void k_prep_weff(const float* __restrict__ wup, const float* __restrict__ wtail,
                                                   float* __restrict__ weff){
  int idx = blockIdx.x*256 + threadIdx.x;     // 110592 exactly
  int rx = idx & 3;
  int px = (idx >> 2) & 1;
  int base = idx >> 3;
  int o  = base % 3;
  int t2 = base / 3;
  int ci = t2 & 63;
  int ry = (t2 >> 6) & 3;
  int py = (t2 >> 8) & 1;
  int e  = t2 >> 9;            // 0..8
  int ex = e % 3, ey = e / 3;
  int ry_off = (py - 2) + ry;
  int rx_off = (px - 2) + rx;
  float acc = 0.f;
  for (int dy=0; dy<3; dy++){
    if (ey==1 && dy==0) continue;
    if (ey==2 && dy==2) continue;
    int pydy = py + dy - 1;
    int sy = ((pydy + 4) >> 1) - 2;
    int vy = (pydy + 4) & 1;
    int a = ry_off + 1 - sy;
    if (a < 0 || a > 2) continue;
    for (int dx=0; dx<3; dx++){
      if (ex==0 && dx==0) continue;
      if (ex==2 && dx==2) continue;
      int pxdx = px + dx - 1;
      int sx = ((pxdx + 4) >> 1) - 2;
      int vx = (pxdx + 4) & 1;
      int b = rx_off + 1 - sx;
      if (b < 0 || b > 2) continue;
      for (int c=0; c<64; c++){
        int u = c*4 + vy*2 + vx;
        acc += wtail[((o*64+c)*3+dy)*3+dx] * wup[((u*64+ci)*3+a)*3+b];
      }
    }
  }
  weff[idx] = acc;
}

// ---------------- head: (x - shift) conv 3->64, init r=h (h in d_out res region), pack signs ----------------
__global__ __launch_bounds__(256) void k_head(const float* __restrict__ x, const float* __restrict__ wh,
                                              float* __restrict__ r, float* __restrict__ h, u64* __restrict__ sgR){
  __shared__ float wl[64*27];
  for (int j=threadIdx.x; j<64*27; j+=256) wl[j] = wh[j];
  __syncthreads();
  const int id = blockIdx.x*256 + threadIdx.x;
  const int n = id >> 14, p = id & 16383;
  const int yy = p >> 7, xx = p & 127;
  float xv[27];
  const float sh[3] = {114.444f, 111.4605f, 103.02f};
  #pragma unroll
  for (int tap=0; tap<9; tap++){
    int Yq = yy + tap/3 - 1, Xq = xx + tap%3 - 1;
    bool v = ((unsigned)Yq < 128u) && ((unsigned)Xq < 128u);
    int q = (Yq << 7) + Xq;
    #pragma unroll
    for (int c=0; c<3; c++)
      xv[c*9+tap] = v ? (x[(size_t)(n*3+c)*HW + q] - sh[c]) : 0.f;
  }
  u64 sg = 0;
  for (int o=0; o<64; o++){
    float acc = 0.f;
    #pragma unroll
    for (int j=0; j<27; j++) acc += wl[o*27+j] * xv[j];
    r[(size_t)(n*64+o)*HW + p] = acc;
    h[(size_t)(n*64+o)*HW + p] = acc;
    sg |= (u64)(acc < 0.f) << o;
  }
  sgR[id] = sg;
}

// ---------------- shared helper: dual-oc-half MFMA over 3x3 taps ----------------
__device__ __forceinline__ void bconv_tile(const char* ring, int so0, int so1, int so2,
                                           int c0bytes, const signed char* wb, int nn, int q,
                                           i32x16& a0, i32x16& a1){
  int soff[3] = {so0, so1, so2};
  #pragma unroll
  for (int dy=0; dy<3; dy++){
    const char* rbase = ring + soff[dy] + c0bytes + nn*80 + q*16;
    #pragma unroll
    for (int dx=0; dx<3; dx++){
      const char* ab = rbase + dx*80;
      const char* wbt = (const char*)wb + (size_t)((dy*3+dx)*64 + nn)*64 + q*16;
      #pragma unroll
      for (int hh=0; hh<2; hh++){
        i32x4 a  = *(const i32x4*)(ab + hh*32);
        i32x4 b0 = *(const i32x4*)(wbt + hh*32);
        i32x4 b1 = *(const i32x4*)(wbt + 2048 + hh*32);
        a0 = __builtin_amdgcn_mfma_i32_32x32x32_i8(a, b0, a0, 0, 0, 0);
        a1 = __builtin_amdgcn_mfma_i32_32x32x32_i8(a, b1, a1, 0, 0, 0);
      }
    }
  }
}

__device__ __forceinline__ void upd_row(float (&rrow)[2][16], const i32x16& a0, const i32x16& a1,
                                        float al0, float al1, float* nv0, float* nv1){
  #pragma unroll
  for (int t=0; t<16; t++){
    rrow[0][t] += al0 * (float)a0[t]; nv0[t] = rrow[0][t];
    rrow[1][t] += al1 * (float)a1[t]; nv1[t] = rrow[1][t];
  }
}

__device__ __forceinline__ void gridbar(int* cnt, int* sns, int nb, int sense, int tid){
  __syncthreads();
  if (tid == 0){
    __threadfence();
    int prev = __hip_atomic_fetch_add(cnt, 1, __ATOMIC_ACQ_REL, __HIP_MEMORY_SCOPE_AGENT);
    if (prev == nb - 1){
      __hip_atomic_store(cnt, 0, __ATOMIC_RELAXED, __HIP_MEMORY_SCOPE_AGENT);
      __hip_atomic_store(sns, sense, __ATOMIC_RELEASE, __HIP_MEMORY_SCOPE_AGENT);
    } else {
      while (__hip_atomic_load(sns, __ATOMIC_ACQUIRE, __HIP_MEMORY_SCOPE_AGENT) < sense)
        __builtin_amdgcn_s_sleep(8);
    }
    __threadfence();
  }
  __syncthreads();
}

// ---------------- persistent body: r in VGPRs across all 16 residual blocks ----------------
// 512 blocks x 256 thr, 2 blocks/CU. Block owns (img n = b>>5, rows y0..y0+3, y0 = (b&31)*4).
// Wave w owns px span 32w..32w+31 (all rows, both oc halves): rreg[4][2][16] = 128 VGPR.
// Per residual block: 8-step ring pipeline: decode sgIn row -> conv1 t-row (i8 to LDS) -> conv2 (reg update),
// then one grid barrier; sign masks ping-pong between sgA/sgB.
__global__ __launch_bounds__(256, 2) void k_persist(const float* __restrict__ rglob,
                                                    u64* __restrict__ sgA, u64* __restrict__ sgB,
                                                    const signed char* __restrict__ wBsg,
                                                    const float* __restrict__ alpha,
                                                    int* __restrict__ bar){
  __shared__ alignas(16) char smem[62880];
  char* sgRg = smem;            // 3 x 132 x 80 = 31680 (sgR sign bytes, col = img col + 2)
  char* tRg  = smem + 31680;    // 3 x 130 x 80 = 31200 (t sign bytes, col = t col + 1)

  const int tid  = threadIdx.x;
  const int b    = blockIdx.x;
  const int n    = b >> 5;
  const int y0   = (b & 31) << 2;
  const int lane = tid & 63;
  const int wid  = tid >> 6;
  const int nn   = lane & 31;
  const int q    = lane >> 5;

  // ---- load r into registers (C-layout: px = 32*wid + (reg&3)+8*(reg>>2)+4q, oc = 32*och+nn) ----
  float rreg[4][2][16];
  #pragma unroll
  for (int rr=0; rr<4; rr++)
    #pragma unroll
    for (int och=0; och<2; och++)
      #pragma unroll
      for (int k2=0; k2<4; k2++){
        f32x4 v = *(const f32x4*)(rglob + (size_t)(n*64 + och*32 + nn)*HW + (y0+rr)*128 + wid*32 + q*4 + k2*8);
        #pragma unroll
        for (int j=0; j<4; j++) rreg[rr][och][k2*4+j] = v[j];
      }

  int sense = 0;
  for (int i=0; i<16; i++){
    const u64* inb = (i & 1) ? sgB : sgA;
    u64* outb      = (i & 1) ? sgA : sgB;
    const signed char* wb1 = wBsg + (size_t)(2*i)*36864;
    const signed char* wb2 = wb1 + 36864;
    const float al0 = alpha[(2*i+1)*64 + nn];
    const float al1 = alpha[(2*i+1)*64 + 32 + nn];

    for (int k=0; k<8; k++){
      // ---- decode sgIn row (y0-2+k) -> i8 ring ----
      {
        int ry = y0 - 2 + k;
        int slotD = (ry + 6) % 3;
        for (int c = tid; c < 132; c += 256){
          u64 neg = 0, pos = 0;
          int ic = c - 2;
          if (((unsigned)ry < 128u) && ((unsigned)ic < 128u)){
            u64 sg = inb[(n<<14) + (ry<<7) + ic];
            neg = sg; pos = ~sg;
          }
          u32 plo=(u32)pos, phi=(u32)(pos>>32), nlo=(u32)neg, nhi=(u32)(neg>>32);
          u32 tmp[16];
          #pragma unroll
          for (int t2=0; t2<16; t2++){
            u32 np = ((t2<8) ? (plo >> (4*t2)) : (phi >> (4*t2-32))) & 0xFu;
            u32 nm = ((t2<8) ? (nlo >> (4*t2)) : (nhi >> (4*t2-32))) & 0xFu;
            u32 bp = (np * 0x00204081u) & 0x01010101u;
            u32 bn = (nm * 0x00204081u) & 0x01010101u;
            tmp[t2] = bp | (bn * 0xFFu);
          }
          i32x4* dst = (i32x4*)(sgRg + slotD*10560 + c*80);
          #pragma unroll
          for (int kk=0; kk<4; kk++){
            i32x4 v; v[0]=(int)tmp[4*kk]; v[1]=(int)tmp[4*kk+1]; v[2]=(int)tmp[4*kk+2]; v[3]=(int)tmp[4*kk+3];
            dst[kk] = v;
          }
        }
      }
      __syncthreads();

      // ---- conv1: t row ty = y0-3+k (i8 into t-ring; t padded rows/cols stay zero) ----
      if (k >= 2){
        int ty = y0 - 3 + k;
        int slotT = (ty + 6) % 3;
        char* tslot = tRg + slotT*10400;
        if ((unsigned)ty >= 128u){
          for (int idx = tid; idx < 2600; idx += 256) ((u32*)tslot)[idx] = 0;
        } else {
          if (tid < 8){
            int col = (tid < 4) ? 0 : 129;
            ((i32x4*)(tslot + col*80))[tid & 3] = (i32x4){0,0,0,0};
          }
          i32x16 a0, a1;
          #pragma unroll
          for (int t=0; t<16; t++){ a0[t]=0; a1[t]=0; }
          bconv_tile(sgRg, ((ty-1+6)%3)*10560, ((ty+6)%3)*10560, ((ty+1+6)%3)*10560,
                     (32*wid + 1)*80, wb1, nn, q, a0, a1);
          #pragma unroll
          for (int reg=0; reg<16; reg++){
            int tc = 32*wid + (reg&3) + ((reg>>2)<<3) + 4*q;
            char* p = tslot + (tc+1)*80 + nn;
            int v0 = a0[reg], v1 = a1[reg];
            p[0]  = (signed char)((v0>0) - (v0<0));
            p[32] = (signed char)((v1>0) - (v1<0));
          }
        }
      }
      __syncthreads();

      // ---- conv2: row cy = y0-4+k: r += alpha*S (registers), emit new sign bits ----
      if (k >= 4){
        int cy = y0 - 4 + k;
        i32x16 a0, a1;
        #pragma unroll
        for (int t=0; t<16; t++){ a0[t]=0; a1[t]=0; }
        bconv_tile(tRg, ((cy-1+6)%3)*10400, ((cy+6)%3)*10400, ((cy+1+6)%3)*10400,
                   (32*wid)*80, wb2, nn, q, a0, a1);
        float nv0[16], nv1[16];
        switch (k){
          case 4: upd_row(rreg[0], a0, a1, al0, al1, nv0, nv1); break;
          case 5: upd_row(rreg[1], a0, a1, al0, al1, nv0, nv1); break;
          case 6: upd_row(rreg[2], a0, a1, al0, al1, nv0, nv1); break;
          default: upd_row(rreg[3], a0, a1, al0, al1, nv0, nv1); break;
        }
        u32 s0 = 0, s1 = 0;
        #pragma unroll
        for (int reg=0; reg<16; reg++){
          int px0 = (reg&3) + ((reg>>2)<<3);
          u64 b0 = __ballot(nv0[reg] < 0.f);
          u64 b1 = __ballot(nv1[reg] < 0.f);
          s0 = (lane==px0  ) ? (u32)b0       : s0;
          s0 = (lane==px0+4) ? (u32)(b0>>32) : s0;
          s1 = (lane==px0  ) ? (u32)b1       : s1;
          s1 = (lane==px0+4) ? (u32)(b1>>32) : s1;
        }
        if (lane < 32){
          int p = (n<<14) + (cy<<7) + (wid<<5) + lane;
          ((u32*)outb)[p*2]     = s0;
          ((u32*)outb)[p*2 + 1] = s1;
        }
      }
      __syncthreads();
    }
    sense++;
    gridbar(bar, bar+1, (int)gridDim.x, sense, tid);
  }
}

// ---------------- MFMA binary conv (fallback path + last conv) ----------------
template<int MODE>
__global__ __launch_bounds__(256) void k_bconv(const u64* __restrict__ sgIn, const u64* __restrict__ nzIn,
                                               const signed char* __restrict__ wB, const float* __restrict__ alphaC,
                                               float* __restrict__ rbuf, u64* __restrict__ sgOut,
                                               u64* __restrict__ nzOut, float* __restrict__ resbuf){
  __shared__ signed char Abytes[4*68*80];

  const int bx = blockIdx.x;
  const int n  = bx >> 7;
  const int rem = bx & 127;
  const int y0 = (rem >> 1) << 1;
  const int x0 = (rem & 1) << 6;

  const int lane = threadIdx.x & 63;
  const int wid  = threadIdx.x >> 6;
  const int rrow = wid >> 1;
  const int och  = wid & 1;
  const int nn   = lane & 31;
  const int q    = lane >> 5;

  i32x4 Bf[9][2];
  #pragma unroll
  for (int t=0;t<9;t++)
    #pragma unroll
    for (int h=0;h<2;h++)
      Bf[t][h] = *(const i32x4*)(wB + ((size_t)(t*64 + och*32 + nn))*64 + h*32 + q*16);

  for (int s = threadIdx.x; s < 4*66; s += 256){
    int g = s/66, c = s%66;
    int y = y0 + g - 1, xcol = x0 + c - 1;
    u64 pos=0, neg=0;
    if (((unsigned)y < 128u) && ((unsigned)xcol < 128u)){
      int p = (n<<14) + (y<<7) + xcol;
      u64 sg = sgIn[p];
      if (MODE==1){ u64 nz = nzIn[p]; pos = nz & ~sg; neg = nz & sg; }
      else        { pos = ~sg;        neg = sg; }
    }
    u32 plo=(u32)pos, phi=(u32)(pos>>32), nlo=(u32)neg, nhi=(u32)(neg>>32);
    u32 tmp[16];
    #pragma unroll
    for (int i=0;i<16;i++){
      u32 np = ((i<8) ? (plo >> (4*i)) : (phi >> (4*i-32))) & 0xFu;
      u32 nm = ((i<8) ? (nlo >> (4*i)) : (nhi >> (4*i-32))) & 0xFu;
      u32 bp = (np * 0x00204081u) & 0x01010101u;
      u32 bn = (nm * 0x00204081u) & 0x01010101u;
      tmp[i] = bp | (bn * 0xFFu);
    }
    i32x4* dst = (i32x4*)&Abytes[(g*68 + c)*80];
    #pragma unroll
    for (int k=0;k<4;k++){ i32x4 v; v[0]=(int)tmp[4*k]; v[1]=(int)tmp[4*k+1]; v[2]=(int)tmp[4*k+2]; v[3]=(int)tmp[4*k+3]; dst[k]=v; }
  }
  __syncthreads();

  const float al = (MODE==0) ? 0.f : alphaC[och*32 + nn];

  for (int xh=0; xh<2; xh++){
    i32x16 acc;
    #pragma unroll
    for (int k=0;k<16;k++) acc[k]=0;

    const i32x4* Ap = (const i32x4*)&Abytes[(rrow*68 + xh*32 + nn)*80 + q*16];
    #pragma unroll
    for (int dy=0;dy<3;dy++)
      #pragma unroll
      for (int dx=0;dx<3;dx++){
        const int t = dy*3+dx;
        #pragma unroll
        for (int h=0;h<2;h++){
          i32x4 a = Ap[(dy*68+dx)*5 + h*2];
          acc = __builtin_amdgcn_mfma_i32_32x32x32_i8(a, Bf[t][h], acc, 0, 0, 0);
        }
      }

    const int ybase = y0 + rrow, xbase = x0 + xh*32;

    if (MODE==0){
      u32 sgc=0, nzc=0;
      #pragma unroll
      for (int reg=0; reg<16; reg++){
        u64 bs = __ballot(acc[reg] < 0);
        u64 bn = __ballot(acc[reg] != 0);
        const int px0 = (reg&3) + ((reg>>2)<<3);
        sgc = (lane==px0  ) ? (u32)bs       : sgc;
        sgc = (lane==px0+4) ? (u32)(bs>>32) : sgc;
        nzc = (lane==px0  ) ? (u32)bn       : nzc;
        nzc = (lane==px0+4) ? (u32)(bn>>32) : nzc;
      }
      if (lane < 32){
        int p = (n<<14) + (ybase<<7) + xbase + lane;
        ((u32*)sgOut)[p*2 + och] = sgc;
        ((u32*)nzOut)[p*2 + och] = nzc;
      }
    } else if (MODE==1){
      float newr[16];
      float* rp = rbuf + ((size_t)((n<<6) + och*32 + nn))*HW + (ybase<<7) + xbase;
      #pragma unroll
      for (int k2=0;k2<4;k2++){
        f32x4 rv = *(f32x4*)(rp + 4*q + 8*k2);
        #pragma unroll
        for (int j=0;j<4;j++){ rv[j] += al * (float)acc[4*k2+j]; newr[4*k2+j] = rv[j]; }
        *(f32x4*)(rp + 4*q + 8*k2) = rv;
      }
      u32 sgc=0;
      #pragma unroll
      for (int reg=0; reg<16; reg++){
        u64 b = __ballot(newr[reg] < 0.f);
        const int px0 = (reg&3) + ((reg>>2)<<3);
        sgc = (lane==px0  ) ? (u32)b       : sgc;
        sgc = (lane==px0+4) ? (u32)(b>>32) : sgc;
      }
      if (lane < 32){
        int p = (n<<14) + (ybase<<7) + xbase + lane;
        ((u32*)sgOut)[p*2 + och] = sgc;
      }
    } else {
      float* hp = resbuf + ((size_t)((n<<6) + och*32 + nn))*HW + (ybase<<7) + xbase;
      #pragma unroll
      for (int k2=0;k2<4;k2++){
        f32x4 hv = *(f32x4*)(hp + 4*q + 8*k2);
        #pragma unroll
        for (int j=0;j<4;j++) hv[j] += al * (float)acc[4*k2+j];
        *(f32x4*)(hp + 4*q + 8*k2) = hv;
      }
    }
  }
}

// ---------------- composed tail (interior X), one row per block ----------------
__global__ __launch_bounds__(128) void k_tail(const float* __restrict__ res, const float* __restrict__ weff,
                                              const float* __restrict__ btail, float* __restrict__ out){
  const int x = threadIdx.x;
  const int Y = blockIdx.x;
  const int n = blockIdx.y;
  const int py = Y & 1, y = Y >> 1;
  const int ey = (Y==0) ? 1 : ((Y==255) ? 2 : 0);
  const float* Ws = weff + (size_t)(((ey*3+1)*2+py)) * 6144;
  float acc[3][2] = {{0.f,0.f},{0.f,0.f},{0.f,0.f}};
  for (int ry=0; ry<4; ry++){
    const int yy = y + (py-2) + ry;
    const bool rowv = ((unsigned)yy < 128u);
    const float* Wr = Ws + ry*1536;
    const float* rp = res + (size_t)n*64*HW + yy*128 + x;
    for (int ci=0; ci<64; ci++){
      const float* pp = rp + (size_t)ci*HW;
      float v[5];
      #pragma unroll
      for (int j=0; j<5; j++){
        int xxc = x - 2 + j;
        v[j] = (rowv && (unsigned)xxc < 128u) ? pp[j-2] : 0.f;
      }
      const float* Wc = Wr + ci*24;
      #pragma unroll
      for (int o=0; o<3; o++)
        #pragma unroll
        for (int px=0; px<2; px++)
          #pragma unroll
          for (int rx=0; rx<4; rx++)
            acc[o][px] += Wc[(o*2+px)*4+rx] * v[px+rx];
    }
  }
  const float sh[3] = {114.444f, 111.4605f, 103.02f};
  #pragma unroll
  for (int o=0; o<3; o++){
    #pragma unroll
    for (int px=0; px<2; px++){
      int X = 2*x + px;
      if (X == 0 || X == 255) continue;
      out[(size_t)((n*3+o)*256+Y)*256 + X] = acc[o][px] + btail[o] + sh[o];
    }
  }
}

// ---------------- tail edge columns X=0 / X=255 ----------------
__global__ __launch_bounds__(256) void k_border(const float* __restrict__ res, const float* __restrict__ weff,
                                                const float* __restrict__ btail, float* __restrict__ out){
  int t = blockIdx.x*256 + threadIdx.x;
  if (t >= 8192) return;
  int side = t & 1;
  int Y = (t >> 1) & 255;
  int n = t >> 9;
  int X = side ? 255 : 0;
  int px = side, x = side ? 127 : 0;
  int py = Y & 1, y = Y >> 1;
  int ey = (Y==0) ? 1 : ((Y==255) ? 2 : 0);
  int ex = side ? 2 : 0;
  const float* Ws = weff + (size_t)((ey*3+ex)*2+py) * 6144;
  float acc[3] = {0.f,0.f,0.f};
  for (int ry=0; ry<4; ry++){
    int yy = y + (py-2) + ry;
    bool rowv = ((unsigned)yy < 128u);
    const float* rp = res + (size_t)n*64*HW + yy*128;
    for (int ci=0; ci<64; ci++){
      const float* Wc = Ws + ry*1536 + ci*24 + px*4;
      #pragma unroll
      for (int rx=0; rx<4; rx++){
        int xxc = x + (px-2) + rx;
        float v = (rowv && (unsigned)xxc < 128u) ? rp[(size_t)ci*HW + xxc] : 0.f;
        acc[0] += Wc[0*8+rx] * v;
        acc[1] += Wc[1*8+rx] * v;
        acc[2] += Wc[2*8+rx] * v;
      }
    }
  }
  const float sh[3] = {114.444f, 111.4605f, 103.02f};
  for (int o=0; o<3; o++)
    out[(size_t)((n*3+o)*256+Y)*256 + X] = acc[o] + btail[o] + sh[o];
}

extern "C" void kernel_launch(void* const* d_in, const int* in_sizes, int n_in,
                              void* d_out, int out_size, void* d_ws, size_t ws_size,
                              hipStream_t stream) {
  const float* x      = (const float*)d_in[0];
  const float* w_head = (const float*)d_in[1];
  const float* w_body = (const float*)d_in[2];
  const float* w_last = (const float*)d_in[3];
  const float* w_up   = (const float*)d_in[4];
  const float* w_tail = (const float*)d_in[5];
  const float* b_tail = (const float*)d_in[6];

  char* ws = (char*)d_ws;
  float* r     = (float*)(ws + OFF_R);
  u64*  sg0    = (u64*) (ws + OFF_SG0);
  u64*  sg1    = (u64*) (ws + OFF_SG1);
  u64*  nzT    = (u64*) (ws + OFF_NZT);
  signed char* wBsg = (signed char*)(ws + OFF_WBSG);
  float* alpha = (float*)(ws + OFF_ALPHA);
  float* weff  = (float*)(ws + OFF_WEFF);
  int*   bar   = (int*)  (ws + OFF_NZT);   // barrier reuses fallback-only nz area

  float* out = (float*)d_out;        // [16,3,256,256]
  float* res = out + 3145728;        // [16,64,128,128] (holds h until last conv, then res)

  k_prep_wbsg<<<75, 256, 0, stream>>>(w_body, w_last, wBsg, alpha);
  k_prep_weff<<<432, 256, 0, stream>>>(w_up, w_tail, weff);
  k_head<<<1024, 256, 0, stream>>>(x, w_head, r, res, sg0);

  hipMemsetAsync((void*)bar, 0, 64, stream);
  const float* rc = r;
  void* args[6] = {(void*)&rc, (void*)&sg0, (void*)&sg1, (void*)&wBsg, (void*)&alpha, (void*)&bar};
  hipError_t e = hipLaunchCooperativeKernel((void*)k_persist, dim3(512), dim3(256), args, 0, stream);
  if (e != hipSuccess){
    // fallback: proven multi-kernel path (r RMW in global)
    for (int i=0; i<16; i++){
      k_bconv<0><<<2048, 256, 0, stream>>>(sg0, nullptr, wBsg + (size_t)(2*i)*36864,
                                           nullptr, nullptr, sg1, nzT, nullptr);
      k_bconv<1><<<2048, 256, 0, stream>>>(sg1, nzT, wBsg + (size_t)(2*i+1)*36864,
                                           alpha + (2*i+1)*64, r, sg0, nullptr, nullptr);
    }
  }
  k_bconv<2><<<2048, 256, 0, stream>>>(sg0, nullptr, wBsg + (size_t)32*36864,
                                       alpha + 32*64, nullptr, nullptr, nullptr, res);
  k_tail<<<dim3(256,16), 128, 0, stream>>>(res, weff, b_tail, out);
  k_border<<<32, 256, 0, stream>>>(res, weff, b_tail, out);
}

// Round 5
// 1290.231 us; speedup vs baseline: 3.8713x; 3.8713x over previous
//
#include <hip/hip_runtime.h>
#include <stdint.h>

typedef unsigned long long u64;
typedef unsigned int u32;
typedef _Float16 f16;
using i32x4  = __attribute__((ext_vector_type(4))) int;
using i32x16 = __attribute__((ext_vector_type(16))) int;
using f32x4  = __attribute__((ext_vector_type(4))) float;
using f16x4  = __attribute__((ext_vector_type(4))) _Float16;

#define HW 16384   // 128*128

// workspace byte offsets
#define OFF_R      0ull           // f16 [16][64][16384] running r (33.5 MB used)
#define OFF_SG0    67108864ull    // u64 [16][16384] sign ping (sgR)
#define OFF_SG1    69206016ull    // u64 [16][16384] sign pong (sgT)
#define OFF_NZT    71303168ull    // u64 [16][16384] nz of conv1 sums
#define OFF_WBSG   73400320ull    // i8  [33][9 tap][64 oc][64 ci] sign weights
#define OFF_ALPHA  74616832ull    // f32 [33][64]
#define OFF_WEFF   74625280ull    // f32 110592 composed tail weights

// ---------------- prep: i8 sign-weight tensor [conv][tap][oc][ci] + alpha ----------------
__global__ __launch_bounds__(256) void k_prep_wbsg(const float* __restrict__ wbody, const float* __restrict__ wlast,
                                                   signed char* __restrict__ wB, float* __restrict__ alpha){
  int t = blockIdx.x*256 + threadIdx.x;          // 33*9*64 = 19008
  if (t >= 33*9*64) return;
  int o = t & 63, tap = (t>>6)%9, cid = t/(64*9);
  const float* src = (cid < 32) ? (wbody + (size_t)cid*36864) : wlast;   // [o][ci][9]
  u32 d[16];
  #pragma unroll
  for (int c4=0;c4<16;c4++){
    u32 v=0;
    #pragma unroll
    for (int j=0;j<4;j++){
      float w = src[(o*64 + c4*4+j)*9 + tap];
      v |= ((w < 0.f) ? 0xFFu : 0x01u) << (8*j);
    }
    d[c4]=v;
  }
  i32x4* dst = (i32x4*)(wB + ((size_t)(cid*9+tap)*64 + o)*64);
  #pragma unroll
  for (int k=0;k<4;k++){ i32x4 v; v[0]=(int)d[4*k]; v[1]=(int)d[4*k+1]; v[2]=(int)d[4*k+2]; v[3]=(int)d[4*k+3]; dst[k]=v; }
  if (tap==0){
    float s=0.f;
    for (int ci=0;ci<64;ci++)
      #pragma unroll
      for (int tp=0;tp<9;tp++) s += fabsf(src[(o*64+ci)*9+tp]);
    alpha[cid*64+o] = s * (1.0f/576.0f);
  }
}

// ------- prep: composed up->shuffle->tail weights (9 edge variants) -------
__global__ __launch_bounds__(256) void k_prep_weff(const float* __restrict__ wup, const float* __restrict__ wtail,
                                                   float* __restrict__ weff){
  int idx = blockIdx.x*256 + threadIdx.x;     // 110592 exactly
  int rx = idx & 3;
  int px = (idx >> 2) & 1;
  int base = idx >> 3;
  int o  = base % 3;
  int t2 = base / 3;
  int ci = t2 & 63;
  int ry = (t2 >> 6) & 3;
  int py = (t2 >> 8) & 1;
  int e  = t2 >> 9;            // 0..8
  int ex = e % 3, ey = e / 3;
  int ry_off = (py - 2) + ry;
  int rx_off = (px - 2) + rx;
  float acc = 0.f;
  for (int dy=0; dy<3; dy++){
    if (ey==1 && dy==0) continue;
    if (ey==2 && dy==2) continue;
    int pydy = py + dy - 1;
    int sy = ((pydy + 4) >> 1) - 2;
    int vy = (pydy + 4) & 1;
    int a = ry_off + 1 - sy;
    if (a < 0 || a > 2) continue;
    for (int dx=0; dx<3; dx++){
      if (ex==0 && dx==0) continue;
      if (ex==2 && dx==2) continue;
      int pxdx = px + dx - 1;
      int sx = ((pxdx + 4) >> 1) - 2;
      int vx = (pxdx + 4) & 1;
      int b = rx_off + 1 - sx;
      if (b < 0 || b > 2) continue;
      for (int c=0; c<64; c++){
        int u = c*4 + vy*2 + vx;
        acc += wtail[((o*64+c)*3+dy)*3+dx] * wup[((u*64+ci)*3+a)*3+b];
      }
    }
  }
  weff[idx] = acc;
}

// ---------------- head: (x - shift) conv 3->64, init r (f16) = h (f32, in d_out res region), pack signs ----------------
__global__ __launch_bounds__(256) void k_head(const float* __restrict__ x, const float* __restrict__ wh,
                                              f16* __restrict__ r, float* __restrict__ h, u64* __restrict__ sgR){
  __shared__ float wl[64*27];
  for (int j=threadIdx.x; j<64*27; j+=256) wl[j] = wh[j];
  __syncthreads();
  const int id = blockIdx.x*256 + threadIdx.x;
  const int n = id >> 14, p = id & 16383;
  const int yy = p >> 7, xx = p & 127;
  float xv[27];
  const float sh[3] = {114.444f, 111.4605f, 103.02f};
  #pragma unroll
  for (int tap=0; tap<9; tap++){
    int Yq = yy + tap/3 - 1, Xq = xx + tap%3 - 1;
    bool v = ((unsigned)Yq < 128u) && ((unsigned)Xq < 128u);
    int q = (Yq << 7) + Xq;
    #pragma unroll
    for (int c=0; c<3; c++)
      xv[c*9+tap] = v ? (x[(size_t)(n*3+c)*HW + q] - sh[c]) : 0.f;
  }
  u64 sg = 0;
  for (int o=0; o<64; o++){
    float acc = 0.f;
    #pragma unroll
    for (int j=0; j<27; j++) acc += wl[o*27+j] * xv[j];
    f16 rv = (f16)acc;
    r[(size_t)(n*64+o)*HW + p] = rv;
    h[(size_t)(n*64+o)*HW + p] = acc;
    sg |= (u64)((float)rv < 0.f) << o;
  }
  sgR[id] = sg;
}

// ---------------- MFMA binary conv ----------------
// MODE 0: conv1  (in sgR only -> write sgT,nzT)
// MODE 1: conv2  (in sgT,nzT  -> r(f16) += alpha*S, write sgR)
// MODE 2: last   (in sgR only -> res(f32) += alpha*S; res holds h)
template<int MODE>
__global__ __launch_bounds__(256) void k_bconv(const u64* __restrict__ sgIn, const u64* __restrict__ nzIn,
                                               const signed char* __restrict__ wB, const float* __restrict__ alphaC,
                                               f16* __restrict__ rbuf, u64* __restrict__ sgOut,
                                               u64* __restrict__ nzOut, float* __restrict__ resbuf){
  __shared__ signed char Abytes[4*68*80];

  const int bx = blockIdx.x;
  const int n  = bx >> 7;
  const int rem = bx & 127;
  const int y0 = (rem >> 1) << 1;
  const int x0 = (rem & 1) << 6;

  const int lane = threadIdx.x & 63;
  const int wid  = threadIdx.x >> 6;
  const int rrow = wid >> 1;
  const int och  = wid & 1;
  const int nn   = lane & 31;
  const int q    = lane >> 5;

  i32x4 Bf[9][2];
  #pragma unroll
  for (int t=0;t<9;t++)
    #pragma unroll
    for (int h=0;h<2;h++)
      Bf[t][h] = *(const i32x4*)(wB + ((size_t)(t*64 + och*32 + nn))*64 + h*32 + q*16);

  for (int s = threadIdx.x; s < 4*66; s += 256){
    int g = s/66, c = s%66;
    int y = y0 + g - 1, xcol = x0 + c - 1;
    u64 pos=0, neg=0;
    if (((unsigned)y < 128u) && ((unsigned)xcol < 128u)){
      int p = (n<<14) + (y<<7) + xcol;
      u64 sg = sgIn[p];
      if (MODE==1){ u64 nz = nzIn[p]; pos = nz & ~sg; neg = nz & sg; }
      else        { pos = ~sg;        neg = sg; }
    }
    u32 plo=(u32)pos, phi=(u32)(pos>>32), nlo=(u32)neg, nhi=(u32)(neg>>32);
    u32 tmp[16];
    #pragma unroll
    for (int i=0;i<16;i++){
      u32 np = ((i<8) ? (plo >> (4*i)) : (phi >> (4*i-32))) & 0xFu;
      u32 nm = ((i<8) ? (nlo >> (4*i)) : (nhi >> (4*i-32))) & 0xFu;
      u32 bp = (np * 0x00204081u) & 0x01010101u;
      u32 bn = (nm * 0x00204081u) & 0x01010101u;
      tmp[i] = bp | (bn * 0xFFu);
    }
    i32x4* dst = (i32x4*)&Abytes[(g*68 + c)*80];
    #pragma unroll
    for (int k=0;k<4;k++){ i32x4 v; v[0]=(int)tmp[4*k]; v[1]=(int)tmp[4*k+1]; v[2]=(int)tmp[4*k+2]; v[3]=(int)tmp[4*k+3]; dst[k]=v; }
  }
  __syncthreads();

  const float al = (MODE==0) ? 0.f : alphaC[och*32 + nn];

  for (int xh=0; xh<2; xh++){
    i32x16 acc;
    #pragma unroll
    for (int k=0;k<16;k++) acc[k]=0;

    const i32x4* Ap = (const i32x4*)&Abytes[(rrow*68 + xh*32 + nn)*80 + q*16];
    #pragma unroll
    for (int dy=0;dy<3;dy++)
      #pragma unroll
      for (int dx=0;dx<3;dx++){
        const int t = dy*3+dx;
        #pragma unroll
        for (int h=0;h<2;h++){
          i32x4 a = Ap[(dy*68+dx)*5 + h*2];
          acc = __builtin_amdgcn_mfma_i32_32x32x32_i8(a, Bf[t][h], acc, 0, 0, 0);
        }
      }

    const int ybase = y0 + rrow, xbase = x0 + xh*32;

    if (MODE==0){
      u32 sgc=0, nzc=0;
      #pragma unroll
      for (int reg=0; reg<16; reg++){
        u64 bs = __ballot(acc[reg] < 0);
        u64 bn = __ballot(acc[reg] != 0);
        const int px0 = (reg&3) + ((reg>>2)<<3);
        sgc = (lane==px0  ) ? (u32)bs       : sgc;
        sgc = (lane==px0+4) ? (u32)(bs>>32) : sgc;
        nzc = (lane==px0  ) ? (u32)bn       : nzc;
        nzc = (lane==px0+4) ? (u32)(bn>>32) : nzc;
      }
      if (lane < 32){
        int p = (n<<14) + (ybase<<7) + xbase + lane;
        ((u32*)sgOut)[p*2 + och] = sgc;
        ((u32*)nzOut)[p*2 + och] = nzc;
      }
    } else if (MODE==1){
      float newr[16];
      f16* rp = rbuf + ((size_t)((n<<6) + och*32 + nn))*HW + (ybase<<7) + xbase;
      #pragma unroll
      for (int k2=0;k2<4;k2++){
        f16x4 rv4 = *(f16x4*)(rp + 4*q + 8*k2);
        #pragma unroll
        for (int j=0;j<4;j++){
          float rv = (float)rv4[j] + al * (float)acc[4*k2+j];
          rv4[j] = (f16)rv;
          newr[4*k2+j] = (float)rv4[j];   // sign decided on the stored f16 value
        }
        *(f16x4*)(rp + 4*q + 8*k2) = rv4;
      }
      u32 sgc=0;
      #pragma unroll
      for (int reg=0; reg<16; reg++){
        u64 b = __ballot(newr[reg] < 0.f);
        const int px0 = (reg&3) + ((reg>>2)<<3);
        sgc = (lane==px0  ) ? (u32)b       : sgc;
        sgc = (lane==px0+4) ? (u32)(b>>32) : sgc;
      }
      if (lane < 32){
        int p = (n<<14) + (ybase<<7) + xbase + lane;
        ((u32*)sgOut)[p*2 + och] = sgc;
      }
    } else {
      float* hp = resbuf + ((size_t)((n<<6) + och*32 + nn))*HW + (ybase<<7) + xbase;
      #pragma unroll
      for (int k2=0;k2<4;k2++){
        f32x4 hv = *(f32x4*)(hp + 4*q + 8*k2);
        #pragma unroll
        for (int j=0;j<4;j++) hv[j] += al * (float)acc[4*k2+j];
        *(f32x4*)(hp + 4*q + 8*k2) = hv;
      }
    }
  }
}

// ---------------- composed tail (interior X), XCD-swizzled: 2 images per XCD, Y ascending ----------------
__global__ __launch_bounds__(128) void k_tail(const float* __restrict__ res, const float* __restrict__ weff,
                                              const float* __restrict__ btail, float* __restrict__ out){
  const int id = blockIdx.x;          // 4096
  const int xcd = id & 7;
  const int l = id >> 3;              // 0..511
  const int n = xcd*2 + (l & 1);      // 2 images per XCD -> L2 window ~320 KB
  const int Y = l >> 1;               // ascending rows within XCD
  const int x = threadIdx.x;          // 0..127
  const int py = Y & 1, y = Y >> 1;
  const int ey = (Y==0) ? 1 : ((Y==255) ? 2 : 0);
  const float* Ws = weff + (size_t)(((ey*3+1)*2+py)) * 6144;
  float acc[3][2] = {{0.f,0.f},{0.f,0.f},{0.f,0.f}};
  for (int ry=0; ry<4; ry++){
    const int yy = y + (py-2) + ry;
    const bool rowv = ((unsigned)yy < 128u);
    const float* Wr = Ws + ry*1536;
    const float* rp = res + (size_t)n*64*HW + yy*128 + x;
    for (int ci=0; ci<64; ci++){
      const float* pp = rp + (size_t)ci*HW;
      float v[5];
      #pragma unroll
      for (int j=0; j<5; j++){
        int xxc = x - 2 + j;
        v[j] = (rowv && (unsigned)xxc < 128u) ? pp[j-2] : 0.f;
      }
      const float* Wc = Wr + ci*24;
      #pragma unroll
      for (int o=0; o<3; o++)
        #pragma unroll
        for (int px=0; px<2; px++)
          #pragma unroll
          for (int rx=0; rx<4; rx++)
            acc[o][px] += Wc[(o*2+px)*4+rx] * v[px+rx];
    }
  }
  const float sh[3] = {114.444f, 111.4605f, 103.02f};
  #pragma unroll
  for (int o=0; o<3; o++){
    #pragma unroll
    for (int px=0; px<2; px++){
      int X = 2*x + px;
      if (X == 0 || X == 255) continue;
      out[(size_t)((n*3+o)*256+Y)*256 + X] = acc[o][px] + btail[o] + sh[o];
    }
  }
}

// ---------------- tail edge columns X=0 / X=255 ----------------
__global__ __launch_bounds__(256) void k_border(const float* __restrict__ res, const float* __restrict__ weff,
                                                const float* __restrict__ btail, float* __restrict__ out){
  int t = blockIdx.x*256 + threadIdx.x;
  if (t >= 8192) return;
  int side = t & 1;
  int Y = (t >> 1) & 255;
  int n = t >> 9;
  int X = side ? 255 : 0;
  int px = side, x = side ? 127 : 0;
  int py = Y & 1, y = Y >> 1;
  int ey = (Y==0) ? 1 : ((Y==255) ? 2 : 0);
  int ex = side ? 2 : 0;
  const float* Ws = weff + (size_t)((ey*3+ex)*2+py) * 6144;
  float acc[3] = {0.f,0.f,0.f};
  for (int ry=0; ry<4; ry++){
    int yy = y + (py-2) + ry;
    bool rowv = ((unsigned)yy < 128u);
    const float* rp = res + (size_t)n*64*HW + yy*128;
    for (int ci=0; ci<64; ci++){
      const float* Wc = Ws + ry*1536 + ci*24 + px*4;
      #pragma unroll
      for (int rx=0; rx<4; rx++){
        int xxc = x + (px-2) + rx;
        float v = (rowv && (unsigned)xxc < 128u) ? rp[(size_t)ci*HW + xxc] : 0.f;
        acc[0] += Wc[0*8+rx] * v;
        acc[1] += Wc[1*8+rx] * v;
        acc[2] += Wc[2*8+rx] * v;
      }
    }
  }
  const float sh[3] = {114.444f, 111.4605f, 103.02f};
  for (int o=0; o<3; o++)
    out[(size_t)((n*3+o)*256+Y)*256 + X] = acc[o] + btail[o] + sh[o];
}

extern "C" void kernel_launch(void* const* d_in, const int* in_sizes, int n_in,
                              void* d_out, int out_size, void* d_ws, size_t ws_size,
                              hipStream_t stream) {
  const float* x      = (const float*)d_in[0];
  const float* w_head = (const float*)d_in[1];
  const float* w_body = (const float*)d_in[2];
  const float* w_last = (const float*)d_in[3];
  const float* w_up   = (const float*)d_in[4];
  const float* w_tail = (const float*)d_in[5];
  const float* b_tail = (const float*)d_in[6];

  char* ws = (char*)d_ws;
  f16*  r      = (f16*) (ws + OFF_R);
  u64*  sg0    = (u64*) (ws + OFF_SG0);
  u64*  sg1    = (u64*) (ws + OFF_SG1);
  u64*  nzT    = (u64*) (ws + OFF_NZT);
  signed char* wBsg = (signed char*)(ws + OFF_WBSG);
  float* alpha = (float*)(ws + OFF_ALPHA);
  float* weff  = (float*)(ws + OFF_WEFF);

  float* out = (float*)d_out;        // [16,3,256,256]
  float* res = out + 3145728;        // [16,64,128,128] (holds h until last conv, then res)

  k_prep_wbsg<<<75, 256, 0, stream>>>(w_body, w_last, wBsg, alpha);
  k_prep_weff<<<432, 256, 0, stream>>>(w_up, w_tail, weff);
  k_head<<<1024, 256, 0, stream>>>(x, w_head, r, res, sg0);
  for (int i=0; i<16; i++){
    k_bconv<0><<<2048, 256, 0, stream>>>(sg0, nullptr, wBsg + (size_t)(2*i)*36864,
                                         nullptr, nullptr, sg1, nzT, nullptr);
    k_bconv<1><<<2048, 256, 0, stream>>>(sg1, nzT, wBsg + (size_t)(2*i+1)*36864,
                                         alpha + (2*i+1)*64, r, sg0, nullptr, nullptr);
  }
  k_bconv<2><<<2048, 256, 0, stream>>>(sg0, nullptr, wBsg + (size_t)32*36864,
                                       alpha + 32*64, nullptr, nullptr, nullptr, res);
  k_tail<<<4096, 128, 0, stream>>>(res, weff, b_tail, out);
  k_border<<<32, 256, 0, stream>>>(res, weff, b_tail, out);
}